// Round 10
// baseline (127.463 us; speedup 1.0000x reference)
//
#include <hip/hip_runtime.h>
#include <hip/hip_bf16.h>
#include <stdint.h>

#define NS_ 4096
#define M_  8192
#define D_  256
#define TEMP 0.07f
#define EXP_SCALE 20.61707212818536f   // log2(e)/0.07 : exp(sim/T) = exp2(sim*EXP_SCALE)
#define LN2 0.6931471805599453f
#define CQ_ 16                          // col-blocks per rtile (16 x 512 cols)

typedef short bf16x8 __attribute__((ext_vector_type(8)));
typedef float f32x4  __attribute__((ext_vector_type(4)));
typedef unsigned short ushortx4 __attribute__((ext_vector_type(4)));

static __device__ inline unsigned short f2bf(float x) {
    unsigned u = __float_as_uint(x);
    u += 0x7fffu + ((u >> 16) & 1u);
    return (unsigned short)(u >> 16);
}

static __device__ inline float cleanf(float v) {
    return __builtin_isfinite(v) ? v : 0.0f;
}

// async 16B global -> LDS (lane-contiguous LDS destination required)
#define LDS_LOAD16(gp, lp) \
    __builtin_amdgcn_global_load_lds((const __attribute__((address_space(1))) uint32_t*)(gp), \
                                     (__attribute__((address_space(3))) uint32_t*)(lp), 16, 0, 0)

// ---------------- Kernel 1: clean + normalize -> bf16 F, fp32 pos[]; zero denom/cnt/out -
// grid = 1024, block = 256 (4 waves, one wave per paired row)
__global__ __launch_bounds__(256) void knorm(const float* __restrict__ z1,
                                             const float* __restrict__ z2,
                                             short* __restrict__ F,
                                             float* __restrict__ pos,
                                             float* __restrict__ denom,
                                             int* __restrict__ cnt,
                                             float* __restrict__ out) {
    const int wave = threadIdx.x >> 6;
    const int t    = threadIdx.x & 63;
    const int i    = blockIdx.x * 4 + wave;       // 0..NS-1
    const float4* p1 = (const float4*)(z1 + (size_t)i * D_);
    const float4* p2 = (const float4*)(z2 + (size_t)i * D_);
    float4 a = p1[t], b = p2[t];
    a.x = cleanf(a.x); a.y = cleanf(a.y); a.z = cleanf(a.z); a.w = cleanf(a.w);
    b.x = cleanf(b.x); b.y = cleanf(b.y); b.z = cleanf(b.z); b.w = cleanf(b.w);

    float s1 = a.x*a.x + a.y*a.y + a.z*a.z + a.w*a.w;
    float s2 = b.x*b.x + b.y*b.y + b.z*b.z + b.w*b.w;
    float dp = a.x*b.x + a.y*b.y + a.z*b.z + a.w*b.w;
    #pragma unroll
    for (int m = 1; m < 64; m <<= 1) {
        s1 += __shfl_xor(s1, m);
        s2 += __shfl_xor(s2, m);
        dp += __shfl_xor(dp, m);
    }
    const float inv1 = 1.0f / fmaxf(sqrtf(s1), 1e-12f);
    const float inv2 = 1.0f / fmaxf(sqrtf(s2), 1e-12f);

    ushortx4 o1, o2;
    o1.x = f2bf(a.x * inv1); o1.y = f2bf(a.y * inv1); o1.z = f2bf(a.z * inv1); o1.w = f2bf(a.w * inv1);
    o2.x = f2bf(b.x * inv2); o2.y = f2bf(b.y * inv2); o2.z = f2bf(b.z * inv2); o2.w = f2bf(b.w * inv2);
    ((ushortx4*)(F + (size_t)i * D_))[t]          = o1;
    ((ushortx4*)(F + (size_t)(i + NS_) * D_))[t]  = o2;

    if (t == 0) pos[i] = dp * inv1 * inv2;                 // exact fp32 positive sim
    const int gid = blockIdx.x * 256 + threadIdx.x;
    if (gid < M_)  denom[gid] = 0.0f;
    if (gid < 64)  cnt[gid] = 0;
    if (gid == 0)  out[0] = 0.0f;
}

// ---------------- Kernel 2: fused sim-GEMM + row exp-sums + finishers -------------------
// grid = 1024 = 64 rtiles (128 rows) x 16 col-blocks (512 cols); 256 thr / 4 waves.
// Wave w owns rows R0 + w*32 + [0,32) as 2 strips of 16: afrag[2][8] = 64 VGPR, K=256
// resident. launch_bounds(256,3): reg cap ~170 -> 3 waves/SIMD, NO spill (R6's (256,4)
// forced a 128-reg squeeze -> 30 MB scratch storm; this is the same geometry, un-squeezed).
// B: 8 tiles of 64 cols staged via global_load_lds + XOR swizzle (2-way-conflict reads).
__global__ __launch_bounds__(256, 3) void kgemm(const short* __restrict__ F,
                                                float* __restrict__ denom,
                                                int* __restrict__ cnt,
                                                const float* __restrict__ pos,
                                                float* __restrict__ out) {
    __shared__ short Bl[64 * 256];   // 32 KB staging tile, 16B chunks XOR-swizzled
    __shared__ int lastflag;
    __shared__ float red[4];

    const int rtile = blockIdx.x >> 4;   // 64 rtiles
    const int cq    = blockIdx.x & 15;   // 16 col-blocks
    const int R0 = rtile * 128;
    const int C0 = cq * 512;

    const int tid  = threadIdx.x;
    const int lane = tid & 63;
    const int wave = tid >> 6;
    const int c16  = lane & 15;
    const int quad = lane >> 4;
    const int swz  = c16 & 7;

    // ---- A prologue: 2 chunks of 64 rows staged coalesced; waves extract their strips
    bf16x8 afrag[2][8];
    #pragma unroll
    for (int ch = 0; ch < 2; ++ch) {
        __syncthreads();
        const short* ga = F + (size_t)(R0 + ch * 64) * D_;
        #pragma unroll
        for (int r2 = 0; r2 < 8; ++r2) {
            int c   = tid + r2 * 256;
            int row = c >> 5;
            int kg  = (c & 31) ^ (row & 7);
            LDS_LOAD16(ga + row * D_ + kg * 8, Bl + c * 8);
        }
        __syncthreads();
        if ((wave >> 1) == ch) {
            #pragma unroll
            for (int s = 0; s < 2; ++s) {
                const int lr = (wave & 1) * 32 + s * 16 + c16;
                #pragma unroll
                for (int ks = 0; ks < 8; ++ks)
                    afrag[s][ks] = *(const bf16x8*)(Bl + lr * 256 +
                                                    (((ks * 4 + quad) ^ swz) * 8));
            }
        }
    }

    float accexp[2][4];
    #pragma unroll
    for (int s = 0; s < 2; ++s)
        #pragma unroll
        for (int r = 0; r < 4; ++r) accexp[s][r] = 0.0f;

    // ---- main loop: 8 B-groups of 64 cols
    for (int it = 0; it < 8; ++it) {
        __syncthreads();                       // previous tile's reads done
        const short* gb = F + (size_t)(C0 + it * 64) * D_;
        #pragma unroll
        for (int r2 = 0; r2 < 8; ++r2) {
            int c   = tid + r2 * 256;
            int row = c >> 5;
            int kg  = (c & 31) ^ (row & 7);
            LDS_LOAD16(gb + row * D_ + kg * 8, Bl + c * 8);
        }
        __syncthreads();                       // staging complete

        #pragma unroll
        for (int sub = 0; sub < 4; ++sub) {
            const int tc = sub * 16 + c16;     // tile col owned by this lane
            const short* bbase = Bl + tc * 256;
            bf16x8 bfrag[8];
            #pragma unroll
            for (int ks = 0; ks < 8; ++ks)
                bfrag[ks] = *(const bf16x8*)(bbase + (((ks * 4 + quad) ^ swz) * 8));

            f32x4 acc0 = (f32x4){0.f, 0.f, 0.f, 0.f};
            f32x4 acc1 = (f32x4){0.f, 0.f, 0.f, 0.f};
            #pragma unroll
            for (int ks = 0; ks < 8; ++ks) {
                acc0 = __builtin_amdgcn_mfma_f32_16x16x32_bf16(
                    afrag[0][ks], bfrag[ks], acc0, 0, 0, 0);
                acc1 = __builtin_amdgcn_mfma_f32_16x16x32_bf16(
                    afrag[1][ks], bfrag[ks], acc1, 0, 0, 0);
            }

            const int colbase = C0 + it * 64 + sub * 16;
            #pragma unroll
            for (int s = 0; s < 2; ++s) {
                const f32x4 acc = s ? acc1 : acc0;
                const int rowbase = R0 + wave * 32 + s * 16;
                if (colbase != rowbase) {            // uniform fast path
                    #pragma unroll
                    for (int r = 0; r < 4; ++r)
                        accexp[s][r] += __builtin_amdgcn_exp2f(acc[r] * EXP_SCALE);
                } else {                             // diagonal 16x16 tile: mask row==col
                    #pragma unroll
                    for (int r = 0; r < 4; ++r) {
                        float e = __builtin_amdgcn_exp2f(acc[r] * EXP_SCALE);
                        if (c16 == quad * 4 + r) e = 0.0f;
                        accexp[s][r] += e;
                    }
                }
            }
        }
    }

    // row sums across the 16 lanes holding each row, one atomic per row
    #pragma unroll
    for (int s = 0; s < 2; ++s)
        #pragma unroll
        for (int r = 0; r < 4; ++r) {
            float v = accexp[s][r];
            v += __shfl_xor(v, 1);
            v += __shfl_xor(v, 2);
            v += __shfl_xor(v, 4);
            v += __shfl_xor(v, 8);
            if (c16 == 0)
                atomicAdd(&denom[R0 + wave * 32 + s * 16 + quad * 4 + r], v);
        }

    // last of 16 blocks per rtile: sum(log(denom[R0..R0+128))) / M -> out (+ pos term)
    __syncthreads();
    if (tid == 0) {
        __threadfence();                              // release our denom adds
        lastflag = (atomicAdd(&cnt[rtile], 1) == CQ_ - 1);
    }
    __syncthreads();
    if (lastflag) {
        float p = 0.0f;
        if (tid < 128) {
            __threadfence();                          // acquire others' denom adds
            float v = atomicAdd(&denom[R0 + tid], 0.0f);  // device-coherent read
            p = __builtin_amdgcn_logf(v) * (LN2 / (float)M_);
        }
        #pragma unroll
        for (int m = 1; m < 64; m <<= 1) p += __shfl_xor(p, m);
        if (lane == 0) red[wave] = p;
        __syncthreads();
        if (tid == 0) atomicAdd(out, red[0] + red[1] + red[2] + red[3]);
        if (rtile == 0) {                             // pos ready (knorm precedes)
            __syncthreads();                          // protect red reuse
            float sp = 0.0f;
            for (int i = tid; i < NS_; i += 256) sp += pos[i];
            #pragma unroll
            for (int m = 1; m < 64; m <<= 1) sp += __shfl_xor(sp, m);
            if (lane == 0) red[wave] = sp;
            __syncthreads();
            if (tid == 0)
                atomicAdd(out, (red[0] + red[1] + red[2] + red[3]) *
                               (-2.0f / (TEMP * (float)M_)));
        }
    }
}

extern "C" void kernel_launch(void* const* d_in, const int* in_sizes, int n_in,
                              void* d_out, int out_size, void* d_ws, size_t ws_size,
                              hipStream_t stream) {
    const float* z1 = (const float*)d_in[0];
    const float* z2 = (const float*)d_in[1];

    short* F     = (short*)d_ws;                                   // 4 MB
    float* denom = (float*)((char*)d_ws + (size_t)M_ * D_ * 2);    // 32 KB
    int*   cnt   = (int*)(denom + M_);                             // 256 B
    float* pos   = (float*)(cnt + 64);                             // 16 KB
    float* out   = (float*)d_out;

    knorm<<<NS_ / 4, 256, 0, stream>>>(z1, z2, F, pos, denom, cnt, out);
    kgemm<<<64 * CQ_, 256, 0, stream>>>(F, denom, cnt, pos, out);
}